// Round 1
// baseline (606.345 us; speedup 1.0000x reference)
//
#include <hip/hip_runtime.h>
#include <hip/hip_bf16.h>

// B=64, S=1024, D=1024, H=64, E=8
#define B_  64
#define S_  1024
#define D_  1024
#define H_  64
#define E_  8
#define EPS_ 1e-5f

typedef __attribute__((ext_vector_type(8))) __bf16 bf16x8;
typedef __attribute__((ext_vector_type(4))) __bf16 bf16x4;
typedef __attribute__((ext_vector_type(4))) float f32x4;

// ---------------------------------------------------------------------------
// Kernel W: pre-swizzle W_down / W_up (f32) into bf16 MFMA-B-fragment layout.
// Layout: [e][ks][nc][lane][j=8] where element = W[k][n],
//   k = ks*32 + (lane>>4)*8 + j, n = nc*16 + (lane&15)
// Wd: K=1024 (ks 0..31), N=64 (nc 0..3). Wu: K=64 (ks 0..1), N=1024 (nc 0..63).
// ---------------------------------------------------------------------------
__global__ __launch_bounds__(256) void swz_kernel(
    const float* __restrict__ Wd, const float* __restrict__ Wu,
    __bf16* __restrict__ wd_swz, __bf16* __restrict__ wu_swz)
{
    int t = blockIdx.x * 256 + threadIdx.x;   // 131072 threads
    if (t < 65536) {                          // Wd: 8 * 32 * 4 * 64 = 65536 chunks
        int e = t >> 13, rem = t & 8191;
        int ks = rem >> 8, nc = (rem >> 6) & 3, lane = rem & 63;
        int k0 = ks * 32 + (lane >> 4) * 8, n = nc * 16 + (lane & 15);
        bf16x8 o;
#pragma unroll
        for (int j = 0; j < 8; ++j)
            o[j] = (__bf16)Wd[((size_t)e * D_ + k0 + j) * H_ + n];
        *(bf16x8*)(wd_swz + (size_t)t * 8) = o;
    } else {                                  // Wu: 8 * 2 * 64 * 64 = 65536 chunks
        int t2 = t - 65536;
        int e = t2 >> 13, rem = t2 & 8191;
        int ks = rem >> 12, nc = (rem >> 6) & 63, lane = rem & 63;
        int k0 = ks * 32 + (lane >> 4) * 8, n = nc * 16 + (lane & 15);
        bf16x8 o;
#pragma unroll
        for (int j = 0; j < 8; ++j)
            o[j] = (__bf16)Wu[((size_t)e * H_ + k0 + j) * D_ + n];
        *(bf16x8*)(wu_swz + (size_t)t2 * 8) = o;
    }
}

// ---------------------------------------------------------------------------
// Kernel A: LayerNorm. 4 waves/block, 1 row per wave per iter, 32 rows/block.
// Writes z (bf16) and per-block column partial sums (f32, exact pre-rounding).
// ---------------------------------------------------------------------------
__global__ __launch_bounds__(256) void ln_kernel(
    const float* __restrict__ x, const float* __restrict__ ln_g,
    const float* __restrict__ ln_b,
    __bf16* __restrict__ z, float* __restrict__ zpart)
{
    const int lane = threadIdx.x & 63, w = threadIdx.x >> 6;
    const int b = blockIdx.x >> 5, sblk = blockIdx.x & 31;   // 32 blocks / batch
    __shared__ float accs[D_];
    for (int i = threadIdx.x; i < D_; i += 256) accs[i] = 0.f;
    __syncthreads();

    float part[16];
#pragma unroll
    for (int i = 0; i < 16; ++i) part[i] = 0.f;

    for (int it = 0; it < 8; ++it) {
        int s = sblk * 32 + it * 4 + w;
        const float* xr = x + ((size_t)b * S_ + s) * D_;
        f32x4 v[4];
        float s1 = 0.f, s2 = 0.f;
#pragma unroll
        for (int j = 0; j < 4; ++j) {
            v[j] = *(const f32x4*)(xr + j * 256 + lane * 4);
#pragma unroll
            for (int tt = 0; tt < 4; ++tt) { s1 += v[j][tt]; s2 += v[j][tt] * v[j][tt]; }
        }
#pragma unroll
        for (int o = 32; o; o >>= 1) { s1 += __shfl_xor(s1, o); s2 += __shfl_xor(s2, o); }
        float mu = s1 * (1.f / D_);
        float var = s2 * (1.f / D_) - mu * mu;
        float rs = rsqrtf(var + EPS_);

        __bf16 zb[16];
#pragma unroll
        for (int j = 0; j < 4; ++j) {
            int c0 = j * 256 + lane * 4;
            f32x4 gg = *(const f32x4*)(ln_g + c0);
            f32x4 bb = *(const f32x4*)(ln_b + c0);
#pragma unroll
            for (int tt = 0; tt < 4; ++tt) {
                float zz = (v[j][tt] - mu) * rs * gg[tt] + bb[tt];
                part[j * 4 + tt] += zz;
                zb[j * 4 + tt] = (__bf16)zz;
            }
        }
        __bf16* zr = z + ((size_t)b * S_ + s) * D_;
#pragma unroll
        for (int j = 0; j < 4; ++j)
            *(bf16x4*)(zr + j * 256 + lane * 4) = *(bf16x4*)&zb[j * 4];
    }

    // combine the 4 waves' column partials in LDS, write one partial per block
#pragma unroll
    for (int j = 0; j < 4; ++j)
#pragma unroll
        for (int tt = 0; tt < 4; ++tt)
            atomicAdd(&accs[j * 256 + lane * 4 + tt], part[j * 4 + tt]);
    __syncthreads();
    float* zp = zpart + ((size_t)b * 32 + sblk) * D_;
    for (int i = threadIdx.x; i < D_; i += 256) zp[i] = accs[i];
}

// ---------------------------------------------------------------------------
// Kernel C: router. One block per batch: reduce 32 partials, BN, D x 8 dot,
// softmax, argmax (first-max, matching jnp.argmax), gate.
// ---------------------------------------------------------------------------
__global__ __launch_bounds__(256) void router_kernel(
    const float* __restrict__ zpart,
    const float* __restrict__ bn_g, const float* __restrict__ bn_b,
    const float* __restrict__ bn_mean, const float* __restrict__ bn_var,
    const float* __restrict__ Wr, const float* __restrict__ br,
    int* __restrict__ idx, float* __restrict__ gate)
{
    const int b = blockIdx.x, tid = threadIdx.x;
    float acc[E_] = {};
    for (int d = tid; d < D_; d += 256) {
        float s = 0.f;
#pragma unroll
        for (int p = 0; p < 32; ++p) s += zpart[((size_t)b * 32 + p) * D_ + d];
        float zb = (s * (1.f / S_) - bn_mean[d]) * rsqrtf(bn_var[d] + EPS_) * bn_g[d] + bn_b[d];
#pragma unroll
        for (int e = 0; e < E_; ++e) acc[e] += zb * Wr[d * E_ + e];
    }
#pragma unroll
    for (int o = 32; o; o >>= 1)
#pragma unroll
        for (int e = 0; e < E_; ++e) acc[e] += __shfl_xor(acc[e], o);

    __shared__ float red[4][E_];
    int lane = tid & 63, w = tid >> 6;
    if (lane == 0)
#pragma unroll
        for (int e = 0; e < E_; ++e) red[w][e] = acc[e];
    __syncthreads();
    if (tid == 0) {
        float logits[E_];
#pragma unroll
        for (int e = 0; e < E_; ++e)
            logits[e] = red[0][e] + red[1][e] + red[2][e] + red[3][e] + br[e];
        float mx = logits[0]; int am = 0;
#pragma unroll
        for (int e = 1; e < E_; ++e) if (logits[e] > mx) { mx = logits[e]; am = e; }
        float den = 0.f;
#pragma unroll
        for (int e = 0; e < E_; ++e) den += expf(logits[e] - mx);
        idx[b] = am;
        gate[b] = 1.f / den;   // exp(mx-mx)/den = prob of the argmax expert
    }
}

// ---------------------------------------------------------------------------
// Kernel D: fused adapter. Block = (batch b, 128-row S-tile), 4 waves.
// Wave owns 32 rows. GEMM1: [32,1024]x[1024,64] -> h, relu(+b_down),
// h -> LDS (XOR-swizzled, kills the stride-128B bank conflict),
// GEMM2: [32,64]x[64,1024] (+b_up) * gate -> out (f32).
// ---------------------------------------------------------------------------
__global__ __launch_bounds__(256) void adapter_kernel(
    const __bf16* __restrict__ z, const __bf16* __restrict__ wd_swz,
    const __bf16* __restrict__ wu_swz,
    const float* __restrict__ b_down, const float* __restrict__ b_up,
    const int* __restrict__ idx, const float* __restrict__ gate,
    float* __restrict__ out)
{
    const int tid = threadIdx.x, lane = tid & 63, w = tid >> 6;
    const int b = blockIdx.x >> 3, tile = blockIdx.x & 7;
    const int e = idx[b];
    const float g = gate[b];
    const int s0 = tile * 128 + w * 32;          // wave's first row
    const int r = lane & 15, kb = lane >> 4;

    // ---- GEMM1: acc[mr][nc] = z[s0+mr*16+..][.] @ Wd ----
    f32x4 acc[2][4] = {};
    const __bf16* zrow0 = z + ((size_t)(b * S_ + s0 + r)) * D_ + kb * 8;
    const __bf16* zrow1 = zrow0 + (size_t)16 * D_;
    const __bf16* wdp = wd_swz + ((size_t)e * 32 * 4 * 64 + lane) * 8;
#pragma unroll 4
    for (int ks = 0; ks < 32; ++ks) {
        bf16x8 a0 = *(const bf16x8*)(zrow0 + ks * 32);
        bf16x8 a1 = *(const bf16x8*)(zrow1 + ks * 32);
        const __bf16* wk = wdp + (size_t)ks * (4 * 64 * 8);
#pragma unroll
        for (int nc = 0; nc < 4; ++nc) {
            bf16x8 bf = *(const bf16x8*)(wk + nc * (64 * 8));
            acc[0][nc] = __builtin_amdgcn_mfma_f32_16x16x32_bf16(a0, bf, acc[0][nc], 0, 0, 0);
            acc[1][nc] = __builtin_amdgcn_mfma_f32_16x16x32_bf16(a1, bf, acc[1][nc], 0, 0, 0);
        }
    }

    // ---- relu(+b_down), store h into wave-private LDS with XOR swizzle ----
    __shared__ __bf16 hlds[4][32 * 64];          // 16 KB
    __bf16* hw = &hlds[w][0];
#pragma unroll
    for (int mr = 0; mr < 2; ++mr)
#pragma unroll
        for (int nc = 0; nc < 4; ++nc)
#pragma unroll
            for (int reg = 0; reg < 4; ++reg) {
                int row = mr * 16 + kb * 4 + reg;
                int col = nc * 16 + r;
                float v = acc[mr][nc][reg] + b_down[e * H_ + col];
                v = fmaxf(v, 0.f);
                int chunk = (col >> 3) ^ (row & 7);
                hw[row * 64 + chunk * 8 + (col & 7)] = (__bf16)v;
            }
    __syncthreads();

    // ---- read A2 fragments (h as MFMA A-operand) ----
    bf16x8 a2[2][2];
#pragma unroll
    for (int mr = 0; mr < 2; ++mr)
#pragma unroll
        for (int ks2 = 0; ks2 < 2; ++ks2) {
            int row = mr * 16 + r;
            int chunk = (ks2 * 4 + kb) ^ (row & 7);
            a2[mr][ks2] = *(const bf16x8*)(hw + row * 64 + chunk * 8);
        }

    // ---- GEMM2 + epilogue ----
    const __bf16* wup = wu_swz + ((size_t)e * 2 * 64 * 64 + lane) * 8;
    float* outp = out + ((size_t)(b * S_ + s0)) * D_;
#pragma unroll 2
    for (int nc2 = 0; nc2 < 64; ++nc2) {
        bf16x8 b0 = *(const bf16x8*)(wup + (size_t)(0 * 64 + nc2) * (64 * 8));
        bf16x8 b1 = *(const bf16x8*)(wup + (size_t)(1 * 64 + nc2) * (64 * 8));
        int d = nc2 * 16 + r;
        float bup = b_up[e * D_ + d];
#pragma unroll
        for (int mr = 0; mr < 2; ++mr) {
            f32x4 acy = {};
            acy = __builtin_amdgcn_mfma_f32_16x16x32_bf16(a2[mr][0], b0, acy, 0, 0, 0);
            acy = __builtin_amdgcn_mfma_f32_16x16x32_bf16(a2[mr][1], b1, acy, 0, 0, 0);
#pragma unroll
            for (int reg = 0; reg < 4; ++reg) {
                int row = mr * 16 + kb * 4 + reg;
                outp[(size_t)row * D_ + d] = (acy[reg] + bup) * g;
            }
        }
    }
}

// ---------------------------------------------------------------------------
extern "C" void kernel_launch(void* const* d_in, const int* in_sizes, int n_in,
                              void* d_out, int out_size, void* d_ws, size_t ws_size,
                              hipStream_t stream)
{
    const float* x       = (const float*)d_in[0];
    const float* ln_g    = (const float*)d_in[1];
    const float* ln_b    = (const float*)d_in[2];
    const float* bn_g    = (const float*)d_in[3];
    const float* bn_b    = (const float*)d_in[4];
    const float* bn_mean = (const float*)d_in[5];
    const float* bn_var  = (const float*)d_in[6];
    const float* Wr      = (const float*)d_in[7];
    const float* br      = (const float*)d_in[8];
    const float* W_down  = (const float*)d_in[9];
    const float* b_down  = (const float*)d_in[10];
    const float* W_up    = (const float*)d_in[11];
    const float* b_up    = (const float*)d_in[12];
    float* out = (float*)d_out;

    // workspace layout (assumes ws_size >= ~145 MB; z bf16 is the big block)
    char* ws = (char*)d_ws;
    __bf16* z       = (__bf16*)(ws);                       // 134217728 B
    float*  zpart   = (float*)(ws + 134217728);            // 8388608 B
    __bf16* wd_swz  = (__bf16*)(ws + 142606336);           // 1048576 B
    __bf16* wu_swz  = (__bf16*)(ws + 143654912);           // 1048576 B
    int*    idx     = (int*)(ws + 144703488);              // 256 B
    float*  gate    = (float*)(ws + 144703744);            // 256 B

    swz_kernel<<<dim3(512), dim3(256), 0, stream>>>(W_down, W_up, wd_swz, wu_swz);
    ln_kernel<<<dim3(B_ * 32), dim3(256), 0, stream>>>(x, ln_g, ln_b, z, zpart);
    router_kernel<<<dim3(B_), dim3(256), 0, stream>>>(zpart, bn_g, bn_b, bn_mean,
                                                      bn_var, Wr, br, idx, gate);
    adapter_kernel<<<dim3(B_ * 8), dim3(256), 0, stream>>>(z, wd_swz, wu_swz,
                                                           b_down, b_up, idx, gate, out);
}